// Round 3
// baseline (208.921 us; speedup 1.0000x reference)
//
#include <hip/hip_runtime.h>
#include <math.h>

#define N 8192
#define D 64
#define CHUNKS 512
#define CROWS 16
#define NQ (2 * N)  // 8192 element-rank queries + 8192 row-threshold queries
#define NBLK 256
#define NTHR 256

typedef unsigned long long u64;

__device__ __forceinline__ unsigned ordered_bits(float v) {
  unsigned u = __float_as_uint(v);
  return u ^ (((int)u >> 31) | 0x80000000u);
}

// Single-use grid barrier: counter pre-zeroed by host memsetAsync.
// Thread 0 arrives with agent-scope ACQ_REL fetch_add (release writes back
// this XCD's L2 so the block's stores -- already drained by the preceding
// __syncthreads' vmcnt(0) -- become device-visible), then spins on ACQUIRE
// loads (invalidate) until all NBLK arrive. Residency margin: 32 KiB LDS
// allows >=2 blocks/CU at any VGPR<=256 (>=1 at any VGPR<=512), so device
// capacity >= 512 slots >= 256 blocks: every block is resident, no deadlock.
__device__ __forceinline__ void gbar(int* bar) {
  __syncthreads();
  if (threadIdx.x == 0) {
    __hip_atomic_fetch_add(bar, 1, __ATOMIC_ACQ_REL, __HIP_MEMORY_SCOPE_AGENT);
    while (__hip_atomic_load(bar, __ATOMIC_ACQUIRE,
                             __HIP_MEMORY_SCOPE_AGENT) < NBLK) {
      __builtin_amdgcn_s_sleep(1);
    }
  }
  __syncthreads();
}

// 256-wide Hillis-Steele inclusive scan (8 steps). All 256 threads call.
__device__ __forceinline__ float hs_scan256(float s, float* sc, int t) {
  sc[t] = s;
  __syncthreads();
  float inc = s;
#pragma unroll
  for (int off = 1; off < 256; off <<= 1) {
    float u_ = (t >= off) ? sc[t - off] : 0.f;
    __syncthreads();
    inc += u_;
    sc[t] = inc;
    __syncthreads();
  }
  return inc;
}

// Single fused kernel: 256 blocks x 256 threads, 4 hand-rolled grid barriers.
__global__ __launch_bounds__(NTHR) void gat_fused(
    const float* __restrict__ x, const float* __restrict__ Wt,
    const float* __restrict__ a1, const float* __restrict__ b1,
    const float* __restrict__ a2, const float* __restrict__ b2,
    float* __restrict__ h, float* __restrict__ f1, float* __restrict__ f2,
    u64* __restrict__ key64, u64* __restrict__ thrkey, int* __restrict__ perm,
    float* __restrict__ wsm, float* __restrict__ wbg, int* __restrict__ ksplit,
    float* __restrict__ Pl, float* __restrict__ Sl, float* __restrict__ pl,
    float* __restrict__ sl, float* __restrict__ tot_s,
    float* __restrict__ tot_b, float* __restrict__ tots_sc,
    float* __restrict__ totb_sc, float* __restrict__ off_s,
    float* __restrict__ off_b, float* __restrict__ poff,
    float* __restrict__ soff, float* __restrict__ out, int* bars) {
  __shared__ __align__(16) u64 ksl[4096];  // 32 KiB; phase D reuses as floats
  const int t = threadIdx.x;
  const int bid = blockIdx.x;
  const int lane = t & 63, wv = t >> 6;

  // ---- Phase A (was K1): h = x@Wt, f1/f2, strictly-distinct sort keys ----
  {
    float wcol[D];
#pragma unroll
    for (int k = 0; k < D; ++k) wcol[k] = Wt[k * D + lane];  // coalesced
    float a1d = a1[lane], a2d = a2[lane];
    float b1v = b1[0], b2v = b2[0];
    int rowBase = bid * 32;
#pragma unroll
    for (int it = 0; it < 8; ++it) {
      int grow = rowBase + wv + it * 4;
      float xv = x[grow * D + lane];
      float acc = 0.f;
#pragma unroll
      for (int k = 0; k < D; ++k) acc += __shfl(xv, k) * wcol[k];
      h[grow * D + lane] = acc;
      float v1 = acc * a1d, v2 = acc * a2d;
#pragma unroll
      for (int off = 32; off > 0; off >>= 1) {
        v1 += __shfl_xor(v1, off);
        v2 += __shfl_xor(v2, off);
      }
      if (lane == 0) {
        float F1 = v1 + b1v, F2 = v2 + b2v;
        f1[grow] = F1;
        f2[grow] = F2;
        key64[grow] = ((u64)ordered_bits(F2) << 13) | (unsigned)grow;
        thrkey[grow] = ((u64)ordered_bits(-F1) << 13);
      }
    }
  }
  gbar(bars + 0);

  // ---- Phase B (fuses K2a+K2b): full counting rank + direct scatter ----
  // 64 queries/block, 4 threads/query. All 8192 keys streamed through LDS
  // in two 4096-key passes. No part[] round-trip, no reduce kernel.
  {
    int q = bid * 64 + (t >> 2);
    int sub = t & 3;
    u64 qv = (q < N) ? key64[q] : thrkey[q - N];
    int cnt = 0;
#pragma unroll
    for (int p = 0; p < 2; ++p) {
      const u64* kp = key64 + p * 4096;
#pragma unroll
      for (int i = 0; i < 16; ++i) ksl[t + i * 256] = kp[t + i * 256];
      __syncthreads();
      // Each thread counts a 1024-key subrange as 512 adjacent pairs.
      // Pair index staggered by sub: the wave's 4 distinct ds_read_b128
      // addresses land on disjoint bank quads {4j..}{4j+4..}{4j+8..}{4j+12..}.
      const u64* kb = ksl + sub * 1024;
#pragma unroll 4
      for (int j = 0; j < 512; ++j) {
        int jj = (j + sub) & 511;
        u64 k0 = kb[2 * jj], k1 = kb[2 * jj + 1];
        cnt += (k0 < qv) ? 1 : 0;
        cnt += (k1 < qv) ? 1 : 0;
      }
      __syncthreads();  // all reads done before next pass overwrites ksl
    }
    cnt += __shfl_xor(cnt, 1);
    cnt += __shfl_xor(cnt, 2);
    if (sub == 0) {
      if (q < N) {
        float v = f2[q];
        perm[cnt] = q;
        wsm[cnt] = expf(0.2f * v);
        wbg[cnt] = expf(v);
      } else {
        ksplit[q - N] = cnt;
      }
    }
  }
  gbar(bars + 1);

  // ---- Phase C (was K3): per-chunk local scans; waves 0-1 own chunks ----
  if (wv < 2) {
    int c = bid * 2 + wv;
    int base = c * CROWS;
    int dd = lane;
    int pj = (dd < CROWS) ? perm[base + dd] : 0;
    float wS = (dd < CROWS) ? wsm[base + dd] : 0.f;
    float wB = (dd < CROWS) ? wbg[base + dd] : 0.f;
    float hv[CROWS];
#pragma unroll
    for (int r = 0; r < CROWS; ++r) {
      int j = __shfl(pj, r);
      hv[r] = h[(size_t)j * D + dd];
    }
    // scalar weight scans over lanes 0..15
    float incS = wS, incB = wB;
#pragma unroll
    for (int off = 1; off < CROWS; off <<= 1) {
      float uS = __shfl_up(incS, off);
      float uB = __shfl_up(incB, off);
      if (dd >= off) { incS += uS; incB += uB; }
    }
    float totS = __shfl(incS, CROWS - 1);
    float totB = __shfl(incB, CROWS - 1);
    if (dd < CROWS) {
      pl[base + dd] = incS - wS;           // exclusive prefix (small w)
      sl[base + dd] = totB - (incB - wB);  // inclusive suffix (big w)
    }
    if (dd == 0) { tots_sc[c] = totS; totb_sc[c] = totB; }
    // vector local scans (registers only)
    float runP = 0.f;
#pragma unroll
    for (int r = 0; r < CROWS; ++r) {
      Pl[(size_t)(base + r) * D + dd] = runP;
      runP += __shfl(wS, r) * hv[r];
    }
    tot_s[c * D + dd] = runP;
    float runS = 0.f;
#pragma unroll
    for (int r = CROWS - 1; r >= 0; --r) {
      runS += __shfl(wB, r) * hv[r];
      Sl[(size_t)(base + r) * D + dd] = runS;
    }
    tot_b[c * D + dd] = runS;
  }
  gbar(bars + 2);

  // ---- Phase D (was K3b): chunk-offset scans. 130 block-tasks:
  // 0..63 vector prefix (dim=task), 64..127 vector excl suffix (dim=task-64),
  // 128 scalar prefix, 129 scalar excl suffix. 2 elems/thread + hs_scan256.
  {
    float* sc = (float*)ksl;
    int task = bid;
    if (task < 64) {
      int dd = task;
      float a = tot_s[(size_t)(2 * t) * D + dd];
      float b = tot_s[(size_t)(2 * t + 1) * D + dd];
      float s = a + b;
      float inc = hs_scan256(s, sc, t);
      float ex = inc - s;
      off_s[(2 * t) * D + dd] = ex;
      off_s[(2 * t + 1) * D + dd] = ex + a;
      if (t == 255) off_s[CHUNKS * D + dd] = inc;  // sentinel: full total
      if (t == 0) Pl[(size_t)N * D + dd] = 0.f;
    } else if (task < 128) {
      int dd = task - 64;
      int c0 = 511 - 2 * t, c1 = 510 - 2 * t;  // reversed traversal
      float a = tot_b[(size_t)c0 * D + dd];
      float b = tot_b[(size_t)c1 * D + dd];
      float s = a + b;
      float inc = hs_scan256(s, sc, t);
      float ex = inc - s;  // = sum over chunks > c0
      off_b[c0 * D + dd] = ex;
      off_b[c1 * D + dd] = ex + a;
      if (t == 0) {
        off_b[CHUNKS * D + dd] = 0.f;  // sentinel
        Sl[(size_t)N * D + dd] = 0.f;
      }
    } else if (task == 128) {
      float a = tots_sc[2 * t], b = tots_sc[2 * t + 1];
      float s = a + b;
      float inc = hs_scan256(s, sc, t);
      float ex = inc - s;
      poff[2 * t] = ex;
      poff[2 * t + 1] = ex + a;
      if (t == 255) poff[CHUNKS] = inc;
      if (t == 0) pl[N] = 0.f;
    } else if (task == 129) {
      int c0 = 511 - 2 * t, c1 = 510 - 2 * t;
      float a = totb_sc[c0], b = totb_sc[c1];
      float s = a + b;
      float inc = hs_scan256(s, sc, t);
      float ex = inc - s;
      soff[c0] = ex;
      soff[c1] = ex + a;
      if (t == 0) {
        soff[CHUNKS] = 0.f;
        sl[N] = 0.f;
      }
    }
  }
  gbar(bars + 3);

  // ---- Phase E (was K4): combine offsets + local scans at split k; ELU ----
  {
    int T = bid * NTHR + t;
#pragma unroll
    for (int p = 0; p < 8; ++p) {
      int g = T + p * (NBLK * NTHR);
      int row = g >> 6, dd = g & 63;
      float f1v = f1[row];
      int k = ksplit[row];
      int c = k >> 4;  // CROWS == 16; k == N -> sentinel chunk
      float e1 = expf(f1v), e2 = expf(0.2f * f1v);
      float Sv = off_b[c * D + dd] + Sl[(size_t)k * D + dd];
      float Pv = off_s[c * D + dd] + Pl[(size_t)k * D + dd];
      float num = e1 * Sv + e2 * Pv;
      float den = e1 * (soff[c] + sl[k]) + e2 * (poff[c] + pl[k]);
      float v = num / den;
      out[g] = v > 0.f ? v : expm1f(v);
    }
  }
}

extern "C" void kernel_launch(void* const* d_in, const int* in_sizes, int n_in,
                              void* d_out, int out_size, void* d_ws,
                              size_t ws_size, hipStream_t stream) {
  const float* x = (const float*)d_in[0];
  const float* Wt = (const float*)d_in[1];
  const float* a1 = (const float*)d_in[2];
  const float* b1 = (const float*)d_in[3];
  const float* a2 = (const float*)d_in[4];
  const float* b2 = (const float*)d_in[5];
  float* out = (float*)d_out;

  int* bars = (int*)d_ws;  // 4 barrier counters, zeroed per launch
  u64* key64 = (u64*)((char*)d_ws + 16);
  u64* thrkey = key64 + N;
  float* ws = (float*)(thrkey + N);
  float* h = ws;          ws += N * D;
  float* f1 = ws;         ws += N;
  float* f2v = ws;        ws += N;
  float* wsm = ws;        ws += N;
  float* wbg = ws;        ws += N;
  int* perm = (int*)ws;   ws += N;
  int* ksplit = (int*)ws; ws += N;
  float* Pl = ws;         ws += (size_t)(N + 1) * D;
  float* Sl = ws;         ws += (size_t)(N + 1) * D;
  float* tot_s = ws;      ws += CHUNKS * D;
  float* tot_b = ws;      ws += CHUNKS * D;
  float* off_s = ws;      ws += (CHUNKS + 1) * D;
  float* off_b = ws;      ws += (CHUNKS + 1) * D;
  float* pl = ws;         ws += (N + 1);
  float* sl = ws;         ws += (N + 1);
  float* tots_sc = ws;    ws += CHUNKS;
  float* totb_sc = ws;    ws += CHUNKS;
  float* poff = ws;       ws += (CHUNKS + 1);
  float* soff = ws;       ws += (CHUNKS + 1);

  hipMemsetAsync(bars, 0, 4 * sizeof(int), stream);
  gat_fused<<<NBLK, NTHR, 0, stream>>>(
      x, Wt, a1, b1, a2, b2, h, f1, f2v, key64, thrkey, perm, wsm, wbg,
      ksplit, Pl, Sl, pl, sl, tot_s, tot_b, tots_sc, totb_sc, off_s, off_b,
      poff, soff, out, bars);
}

// Round 4
// 140.778 us; speedup vs baseline: 1.4840x; 1.4840x over previous
//
#include <hip/hip_runtime.h>
#include <math.h>

#define N 8192
#define D 64
#define CHUNKS 512
#define CROWS 16
#define NQ (2 * N)  // 8192 element-rank queries + 8192 row-threshold queries

typedef unsigned long long u64;

__device__ __forceinline__ unsigned ordered_bits(float v) {
  unsigned u = __float_as_uint(v);
  return u ^ (((int)u >> 31) | 0x80000000u);
}

// K1: h = x@Wt (Wt column in regs, x row via shfl broadcast); f1/f2; 64-bit
// strictly-distinct sort keys + per-row threshold keys. 16 rows/block.
// (verified round-0 code, unchanged)
__global__ __launch_bounds__(256) void k1_gemm(
    const float* __restrict__ x, const float* __restrict__ Wt,
    const float* __restrict__ a1, const float* __restrict__ b1,
    const float* __restrict__ a2, const float* __restrict__ b2,
    float* __restrict__ h, float* __restrict__ f1, float* __restrict__ f2,
    u64* __restrict__ key64, u64* __restrict__ thrkey) {
  int t = threadIdx.x;
  int lane = t & 63, wv = t >> 6;
  float wcol[D];
#pragma unroll
  for (int k = 0; k < D; ++k) wcol[k] = Wt[k * D + lane];  // coalesced
  float a1d = a1[lane], a2d = a2[lane];
  float b1v = b1[0], b2v = b2[0];
  int rowBase = blockIdx.x * 16;
#pragma unroll
  for (int it = 0; it < 4; ++it) {
    int grow = rowBase + wv + it * 4;
    float xv = x[grow * D + lane];
    float acc = 0.f;
#pragma unroll
    for (int k = 0; k < D; ++k) acc += __shfl(xv, k) * wcol[k];
    h[grow * D + lane] = acc;
    float v1 = acc * a1d, v2 = acc * a2d;
#pragma unroll
    for (int off = 32; off > 0; off >>= 1) {
      v1 += __shfl_xor(v1, off);
      v2 += __shfl_xor(v2, off);
    }
    if (lane == 0) {
      float F1 = v1 + b1v, F2 = v2 + b2v;
      f1[grow] = F1;
      f2[grow] = F2;
      key64[grow] = ((u64)ordered_bits(F2) << 13) | (unsigned)grow;
      thrkey[grow] = ((u64)ordered_bits(-F1) << 13);
    }
  }
}

// K2': full counting rank + direct scatter (replaces K2a+K2b, no part[]).
// 512 blocks x 256 thr; block owns 32 queries. All 8192 keys streamed via
// LDS in two 4096-key tiles. Thread = (q2 = lane&1, s = lane>>1): owns 4
// queries, scans sub-range [s*128,(s+1)*128) of each tile. Lanes with equal
// s broadcast-read the same address; across the 32 s values, addresses land
// 2-way on 16 even banks (free). Reduce over s via shfl_xor {2,4,8,16,32}.
__global__ __launch_bounds__(256) void k2_rank(
    const u64* __restrict__ key64, const u64* __restrict__ thrkey,
    const float* __restrict__ f2, int* __restrict__ perm,
    float* __restrict__ wsm, float* __restrict__ wbg,
    int* __restrict__ ksplit) {
  __shared__ u64 ksl[4096];  // 32 KiB
  int t = threadIdx.x;
  int lane = t & 63, wv = t >> 6;
  int q2 = lane & 1, s = lane >> 1;
  int qbase = blockIdx.x * 32 + wv * 8 + q2 * 4;
  u64 qv[4];
#pragma unroll
  for (int qi = 0; qi < 4; ++qi) {
    int q = qbase + qi;
    qv[qi] = (q < N) ? key64[q] : thrkey[q - N];
  }
  int cnt[4] = {0, 0, 0, 0};
#pragma unroll
  for (int p = 0; p < 2; ++p) {
    const u64* kp = key64 + p * 4096;
#pragma unroll
    for (int i = 0; i < 16; ++i) ksl[t + i * 256] = kp[t + i * 256];
    __syncthreads();
    const u64* kb = ksl + s * 128;
#pragma unroll 8
    for (int j = 0; j < 128; ++j) {
      int jj = (j + s) & 127;  // bank stagger
      u64 k = kb[jj];
      cnt[0] += (k < qv[0]) ? 1 : 0;
      cnt[1] += (k < qv[1]) ? 1 : 0;
      cnt[2] += (k < qv[2]) ? 1 : 0;
      cnt[3] += (k < qv[3]) ? 1 : 0;
    }
    __syncthreads();  // all reads done before next tile overwrites ksl
  }
#pragma unroll
  for (int off = 2; off < 64; off <<= 1) {
#pragma unroll
    for (int qi = 0; qi < 4; ++qi) cnt[qi] += __shfl_xor(cnt[qi], off);
  }
  if (s == 0) {  // lanes 0 (q2=0) and 1 (q2=1) hold the 8 results per wave
#pragma unroll
    for (int qi = 0; qi < 4; ++qi) {
      int q = qbase + qi;
      int rank = cnt[qi];
      if (q < N) {
        float v = f2[q];
        perm[rank] = q;
        wsm[rank] = expf(0.2f * v);
        wbg[rank] = expf(v);
      } else {
        ksplit[q - N] = rank;
      }
    }
  }
}

// K3: per-chunk LOCAL scans (1 chunk per wave, registers only) + totals.
// (verified round-0 code + sentinel-row writes by the chunk-511 wave)
__global__ __launch_bounds__(256) void k3_scan(
    const float* __restrict__ h, const int* __restrict__ perm,
    const float* __restrict__ wsm, const float* __restrict__ wbg,
    float* __restrict__ Pl, float* __restrict__ Sl,
    float* __restrict__ pl, float* __restrict__ sl,
    float* __restrict__ tot_s, float* __restrict__ tot_b,
    float* __restrict__ tots_sc, float* __restrict__ totb_sc) {
  int t = threadIdx.x, lane = t & 63, wv = t >> 6;
  int c = blockIdx.x * 4 + wv;
  int base = c * CROWS;
  int dd = lane;
  int pj = (dd < CROWS) ? perm[base + dd] : 0;
  float wS = (dd < CROWS) ? wsm[base + dd] : 0.f;
  float wB = (dd < CROWS) ? wbg[base + dd] : 0.f;
  float hv[CROWS];
#pragma unroll
  for (int r = 0; r < CROWS; ++r) {
    int j = __shfl(pj, r);
    hv[r] = h[(size_t)j * D + dd];
  }
  // scalar weight scans over lanes 0..15
  float incS = wS, incB = wB;
#pragma unroll
  for (int off = 1; off < CROWS; off <<= 1) {
    float uS = __shfl_up(incS, off);
    float uB = __shfl_up(incB, off);
    if (dd >= off) { incS += uS; incB += uB; }
  }
  float totS = __shfl(incS, CROWS - 1);
  float totB = __shfl(incB, CROWS - 1);
  if (dd < CROWS) {
    pl[base + dd] = incS - wS;           // exclusive prefix (small w)
    sl[base + dd] = totB - (incB - wB);  // inclusive suffix (big w)
  }
  if (dd == 0) { tots_sc[c] = totS; totb_sc[c] = totB; }
  // vector local scans (registers only)
  float runP = 0.f;
#pragma unroll
  for (int r = 0; r < CROWS; ++r) {
    Pl[(size_t)(base + r) * D + dd] = runP;
    runP += __shfl(wS, r) * hv[r];
  }
  tot_s[c * D + dd] = runP;
  float runS = 0.f;
#pragma unroll
  for (int r = CROWS - 1; r >= 0; --r) {
    runS += __shfl(wB, r) * hv[r];
    Sl[(size_t)(base + r) * D + dd] = runS;
  }
  tot_b[c * D + dd] = runS;
  // sentinel rows for k == N (previously written by K3b)
  if (c == CHUNKS - 1) {
    Pl[(size_t)N * D + dd] = 0.f;
    Sl[(size_t)N * D + dd] = 0.f;
    if (dd == 0) { pl[N] = 0.f; sl[N] = 0.f; }
  }
}

// K4': combine + output, recomputing the chunk-offset prefixes in-block
// (replaces K3b+K4). 512 blocks x 256 thr; block owns 16 rows. 4 waves own
// 128-chunk segments: pass 1 = segment totals (both directions), LDS
// combine = segment start offsets, pass 2 ascending snapshots exclusive
// prefixes at the block's c_r set, pass 2b descending snapshots exclusive
// suffixes. c_r == 512 rows get (grand total, 0). Then per-row ELU output.
__global__ __launch_bounds__(256) void k4_out(
    const float* __restrict__ f1, const int* __restrict__ ksplit,
    const float* __restrict__ tot_s, const float* __restrict__ tot_b,
    const float* __restrict__ tots_sc, const float* __restrict__ totb_sc,
    const float* __restrict__ Pl, const float* __restrict__ Sl,
    const float* __restrict__ pl, const float* __restrict__ sl,
    float* __restrict__ out) {
  __shared__ int sh_k[16];
  __shared__ int sh_c[16];
  __shared__ float sh_f1[16];
  __shared__ unsigned map[CHUNKS];     // bitmask of row slots at chunk c
  __shared__ float segP[4][D], segB[4][D];
  __shared__ float segPs[4], segBs[4];
  __shared__ float snapP[16][D], snapS[16][D];
  __shared__ float snapPs[16], snapSs[16];
  int t = threadIdx.x;
  int dd = t & 63, seg = t >> 6;
  int r0 = blockIdx.x * 16;
  map[t] = 0;
  map[t + 256] = 0;
  __syncthreads();
  if (t < 16) {
    int k = ksplit[r0 + t];
    sh_k[t] = k;
    int c = k >> 4;  // CROWS == 16
    sh_c[t] = c;
    sh_f1[t] = f1[r0 + t];
    if (c < CHUNKS) atomicOr(&map[c], 1u << t);
  }
  __syncthreads();
  int cs = seg * 128;
  // pass 1: segment totals (prefix dir over tot_s, suffix dir over tot_b)
  float tP = 0.f, tB = 0.f, tPs = 0.f, tBs = 0.f;
#pragma unroll 4
  for (int j = 0; j < 128; ++j) {
    int c = cs + j;
    tP += tot_s[c * D + dd];
    tB += tot_b[c * D + dd];
    tPs += tots_sc[c];
    tBs += totb_sc[c];
  }
  segP[seg][dd] = tP;
  segB[seg][dd] = tB;
  if (dd == 0) { segPs[seg] = tPs; segBs[seg] = tBs; }
  __syncthreads();
  // segment start offsets + grand totals
  float startP = 0.f, startPs = 0.f;
  for (int s2 = 0; s2 < seg; ++s2) { startP += segP[s2][dd]; startPs += segPs[s2]; }
  float startS = 0.f, startSs = 0.f;
  for (int s2 = seg + 1; s2 < 4; ++s2) { startS += segB[s2][dd]; startSs += segBs[s2]; }
  float grandP = segP[0][dd] + segP[1][dd] + segP[2][dd] + segP[3][dd];
  float grandPs = segPs[0] + segPs[1] + segPs[2] + segPs[3];
  // pass 2: ascending, snapshot exclusive prefix at matching c_r
  float runP = startP, runPs = startPs;
#pragma unroll 4
  for (int j = 0; j < 128; ++j) {
    int c = cs + j;
    unsigned m = map[c];
    while (m) {
      int slot = __ffs(m) - 1;
      m &= m - 1;
      snapP[slot][dd] = runP;
      if (dd == 0) snapPs[slot] = runPs;
    }
    runP += tot_s[c * D + dd];
    runPs += tots_sc[c];
  }
  // pass 2b: descending, snapshot exclusive suffix at matching c_r
  float runS = startS, runSs = startSs;
#pragma unroll 4
  for (int j = 0; j < 128; ++j) {
    int c = cs + 127 - j;
    unsigned m = map[c];
    while (m) {
      int slot = __ffs(m) - 1;
      m &= m - 1;
      snapS[slot][dd] = runS;
      if (dd == 0) snapSs[slot] = runSs;
    }
    runS += tot_b[c * D + dd];
    runSs += totb_sc[c];
  }
  __syncthreads();
  // c_r == 512 rows: prefix = grand total, suffix = 0
  if (seg == 0) {
#pragma unroll
    for (int slot = 0; slot < 16; ++slot) {
      if (sh_c[slot] == CHUNKS) {
        snapP[slot][dd] = grandP;
        snapS[slot][dd] = 0.f;
        if (dd == 0) { snapPs[slot] = grandPs; snapSs[slot] = 0.f; }
      }
    }
  }
  __syncthreads();
  // output: wave seg handles row slots seg*4 .. seg*4+3
#pragma unroll
  for (int ii = 0; ii < 4; ++ii) {
    int slot = seg * 4 + ii;
    int row = r0 + slot;
    int k = sh_k[slot];
    float f1v = sh_f1[slot];
    float e1 = expf(f1v), e2 = expf(0.2f * f1v);
    float Pv = snapP[slot][dd] + Pl[(size_t)k * D + dd];  // k==N: sentinel 0
    float Sv = snapS[slot][dd] + Sl[(size_t)k * D + dd];
    float num = e1 * Sv + e2 * Pv;
    float den = e1 * (snapSs[slot] + sl[k]) + e2 * (snapPs[slot] + pl[k]);
    float v = num / den;
    out[row * D + dd] = v > 0.f ? v : expm1f(v);
  }
}

extern "C" void kernel_launch(void* const* d_in, const int* in_sizes, int n_in,
                              void* d_out, int out_size, void* d_ws,
                              size_t ws_size, hipStream_t stream) {
  const float* x = (const float*)d_in[0];
  const float* Wt = (const float*)d_in[1];
  const float* a1 = (const float*)d_in[2];
  const float* b1 = (const float*)d_in[3];
  const float* a2 = (const float*)d_in[4];
  const float* b2 = (const float*)d_in[5];
  float* out = (float*)d_out;

  u64* key64 = (u64*)d_ws;
  u64* thrkey = key64 + N;
  float* ws = (float*)(thrkey + N);
  float* h = ws;          ws += N * D;
  float* f1 = ws;         ws += N;
  float* f2v = ws;        ws += N;
  float* wsm = ws;        ws += N;
  float* wbg = ws;        ws += N;
  int* perm = (int*)ws;   ws += N;
  int* ksplit = (int*)ws; ws += N;
  float* Pl = ws;         ws += (size_t)(N + 1) * D;
  float* Sl = ws;         ws += (size_t)(N + 1) * D;
  float* tot_s = ws;      ws += CHUNKS * D;
  float* tot_b = ws;      ws += CHUNKS * D;
  float* pl = ws;         ws += (N + 1);
  float* sl = ws;         ws += (N + 1);
  float* tots_sc = ws;    ws += CHUNKS;
  float* totb_sc = ws;    ws += CHUNKS;

  k1_gemm<<<N / 16, 256, 0, stream>>>(x, Wt, a1, b1, a2, b2, h, f1, f2v,
                                      key64, thrkey);
  k2_rank<<<NQ / 32, 256, 0, stream>>>(key64, thrkey, f2v, perm, wsm, wbg,
                                       ksplit);
  k3_scan<<<CHUNKS / 4, 256, 0, stream>>>(h, perm, wsm, wbg, Pl, Sl, pl, sl,
                                          tot_s, tot_b, tots_sc, totb_sc);
  k4_out<<<N / 16, 256, 0, stream>>>(f1, ksplit, tot_s, tot_b, tots_sc,
                                     totb_sc, Pl, Sl, pl, sl, out);
}

// Round 5
// 100.244 us; speedup vs baseline: 2.0841x; 1.4043x over previous
//
#include <hip/hip_runtime.h>
#include <math.h>

#define N 8192
#define D 64
#define CHUNKS 512
#define CROWS 16
#define NQ (2 * N)  // 8192 element-rank queries + 8192 row-threshold queries

typedef unsigned long long u64;

__device__ __forceinline__ unsigned ordered_bits(float v) {
  unsigned u = __float_as_uint(v);
  return u ^ (((int)u >> 31) | 0x80000000u);
}

// K1: h = x@Wt (Wt column in regs, x row via shfl broadcast); f1/f2; 64-bit
// strictly-distinct sort keys + per-row threshold keys. 16 rows/block.
// (verified baseline code, unchanged)
__global__ __launch_bounds__(256) void k1_gemm(
    const float* __restrict__ x, const float* __restrict__ Wt,
    const float* __restrict__ a1, const float* __restrict__ b1,
    const float* __restrict__ a2, const float* __restrict__ b2,
    float* __restrict__ h, float* __restrict__ f1, float* __restrict__ f2,
    u64* __restrict__ key64, u64* __restrict__ thrkey) {
  int t = threadIdx.x;
  int lane = t & 63, wv = t >> 6;
  float wcol[D];
#pragma unroll
  for (int k = 0; k < D; ++k) wcol[k] = Wt[k * D + lane];  // coalesced
  float a1d = a1[lane], a2d = a2[lane];
  float b1v = b1[0], b2v = b2[0];
  int rowBase = blockIdx.x * 16;
#pragma unroll
  for (int it = 0; it < 4; ++it) {
    int grow = rowBase + wv + it * 4;
    float xv = x[grow * D + lane];
    float acc = 0.f;
#pragma unroll
    for (int k = 0; k < D; ++k) acc += __shfl(xv, k) * wcol[k];
    h[grow * D + lane] = acc;
    float v1 = acc * a1d, v2 = acc * a2d;
#pragma unroll
    for (int off = 32; off > 0; off >>= 1) {
      v1 += __shfl_xor(v1, off);
      v2 += __shfl_xor(v2, off);
    }
    if (lane == 0) {
      float F1 = v1 + b1v, F2 = v2 + b2v;
      f1[grow] = F1;
      f2[grow] = F2;
      key64[grow] = ((u64)ordered_bits(F2) << 13) | (unsigned)grow;
      thrkey[grow] = ((u64)ordered_bits(-F1) << 13);
    }
  }
}

// K2': full counting rank + direct scatter (replaces K2a+K2b, no part[]).
// 512 blocks x 256 thr; block owns 32 queries. All 8192 keys streamed via
// LDS in two 4096-key tiles. Thread = (q2 = lane&1, s = lane>>1): owns 4
// queries, scans sub-range [s*128,(s+1)*128) of each tile; bank-staggered.
// Reduce over s via shfl_xor {2,4,8,16,32}. (verified in round 3)
__global__ __launch_bounds__(256) void k2_rank(
    const u64* __restrict__ key64, const u64* __restrict__ thrkey,
    const float* __restrict__ f2, int* __restrict__ perm,
    float* __restrict__ wsm, float* __restrict__ wbg,
    int* __restrict__ ksplit) {
  __shared__ u64 ksl[4096];  // 32 KiB
  int t = threadIdx.x;
  int lane = t & 63, wv = t >> 6;
  int q2 = lane & 1, s = lane >> 1;
  int qbase = blockIdx.x * 32 + wv * 8 + q2 * 4;
  u64 qv[4];
#pragma unroll
  for (int qi = 0; qi < 4; ++qi) {
    int q = qbase + qi;
    qv[qi] = (q < N) ? key64[q] : thrkey[q - N];
  }
  int cnt[4] = {0, 0, 0, 0};
#pragma unroll
  for (int p = 0; p < 2; ++p) {
    const u64* kp = key64 + p * 4096;
#pragma unroll
    for (int i = 0; i < 16; ++i) ksl[t + i * 256] = kp[t + i * 256];
    __syncthreads();
    const u64* kb = ksl + s * 128;
#pragma unroll 8
    for (int j = 0; j < 128; ++j) {
      int jj = (j + s) & 127;  // bank stagger
      u64 k = kb[jj];
      cnt[0] += (k < qv[0]) ? 1 : 0;
      cnt[1] += (k < qv[1]) ? 1 : 0;
      cnt[2] += (k < qv[2]) ? 1 : 0;
      cnt[3] += (k < qv[3]) ? 1 : 0;
    }
    __syncthreads();  // all reads done before next tile overwrites ksl
  }
#pragma unroll
  for (int off = 2; off < 64; off <<= 1) {
#pragma unroll
    for (int qi = 0; qi < 4; ++qi) cnt[qi] += __shfl_xor(cnt[qi], off);
  }
  if (s == 0) {  // lanes 0 (q2=0) and 1 (q2=1) hold the 8 results per wave
#pragma unroll
    for (int qi = 0; qi < 4; ++qi) {
      int q = qbase + qi;
      int rank = cnt[qi];
      if (q < N) {
        float v = f2[q];
        perm[rank] = q;
        wsm[rank] = expf(0.2f * v);
        wbg[rank] = expf(v);
      } else {
        ksplit[q - N] = rank;
      }
    }
  }
}

// K3: per-chunk LOCAL scans (1 chunk per wave, registers only) + totals.
// (verified baseline code, unchanged)
__global__ __launch_bounds__(256) void k3_scan(
    const float* __restrict__ h, const int* __restrict__ perm,
    const float* __restrict__ wsm, const float* __restrict__ wbg,
    float* __restrict__ Pl, float* __restrict__ Sl,
    float* __restrict__ pl, float* __restrict__ sl,
    float* __restrict__ tot_s, float* __restrict__ tot_b,
    float* __restrict__ tots_sc, float* __restrict__ totb_sc) {
  int t = threadIdx.x, lane = t & 63, wv = t >> 6;
  int c = blockIdx.x * 4 + wv;
  int base = c * CROWS;
  int dd = lane;
  int pj = (dd < CROWS) ? perm[base + dd] : 0;
  float wS = (dd < CROWS) ? wsm[base + dd] : 0.f;
  float wB = (dd < CROWS) ? wbg[base + dd] : 0.f;
  float hv[CROWS];
#pragma unroll
  for (int r = 0; r < CROWS; ++r) {
    int j = __shfl(pj, r);
    hv[r] = h[(size_t)j * D + dd];
  }
  // scalar weight scans over lanes 0..15
  float incS = wS, incB = wB;
#pragma unroll
  for (int off = 1; off < CROWS; off <<= 1) {
    float uS = __shfl_up(incS, off);
    float uB = __shfl_up(incB, off);
    if (dd >= off) { incS += uS; incB += uB; }
  }
  float totS = __shfl(incS, CROWS - 1);
  float totB = __shfl(incB, CROWS - 1);
  if (dd < CROWS) {
    pl[base + dd] = incS - wS;           // exclusive prefix (small w)
    sl[base + dd] = totB - (incB - wB);  // inclusive suffix (big w)
  }
  if (dd == 0) { tots_sc[c] = totS; totb_sc[c] = totB; }
  // vector local scans (registers only)
  float runP = 0.f;
#pragma unroll
  for (int r = 0; r < CROWS; ++r) {
    Pl[(size_t)(base + r) * D + dd] = runP;
    runP += __shfl(wS, r) * hv[r];
  }
  tot_s[c * D + dd] = runP;
  float runS = 0.f;
#pragma unroll
  for (int r = CROWS - 1; r >= 0; --r) {
    runS += __shfl(wB, r) * hv[r];
    Sl[(size_t)(base + r) * D + dd] = runS;
  }
  tot_b[c * D + dd] = runS;
}

// K3b: chunk-offset scans, fully parallel. Blocks 0..63: vector prefix for
// dim=blk; 64..127: vector exclusive suffix for dim=blk-64; 128: scalars.
// 512-wide Hillis-Steele in LDS (9 steps). (verified baseline, unchanged)
__global__ __launch_bounds__(512) void k3b_offsets(
    const float* __restrict__ tot_s, const float* __restrict__ tot_b,
    const float* __restrict__ tots_sc, const float* __restrict__ totb_sc,
    float* __restrict__ off_s, float* __restrict__ off_b,
    float* __restrict__ poff, float* __restrict__ soff,
    float* __restrict__ Pl, float* __restrict__ Sl,
    float* __restrict__ pl, float* __restrict__ sl) {
  __shared__ float sc[512];
  int t = threadIdx.x;
  int blk = blockIdx.x;
  if (blk < 64) {
    int dd = blk;
    float v = tot_s[t * D + dd];
    sc[t] = v;
    __syncthreads();
    float inc = v;
#pragma unroll
    for (int off = 1; off < 512; off <<= 1) {
      float u_ = (t >= off) ? sc[t - off] : 0.f;
      __syncthreads();
      inc += u_;
      sc[t] = inc;
      __syncthreads();
    }
    off_s[t * D + dd] = inc - v;
    if (t == 511) off_s[CHUNKS * D + dd] = inc;  // sentinel
    if (t == 0) Pl[(size_t)N * D + dd] = 0.f;
  } else if (blk < 128) {
    int dd = blk - 64;
    int rc = 511 - t;
    float v = tot_b[rc * D + dd];
    sc[t] = v;
    __syncthreads();
    float inc = v;
#pragma unroll
    for (int off = 1; off < 512; off <<= 1) {
      float u_ = (t >= off) ? sc[t - off] : 0.f;
      __syncthreads();
      inc += u_;
      sc[t] = inc;
      __syncthreads();
    }
    off_b[rc * D + dd] = inc - v;  // exclusive suffix
    if (t == 0) {
      off_b[CHUNKS * D + dd] = 0.f;  // sentinel
      Sl[(size_t)N * D + dd] = 0.f;
    }
  } else {
    {  // scalar prefix over tots_sc
      float v = tots_sc[t];
      sc[t] = v;
      __syncthreads();
      float inc = v;
#pragma unroll
      for (int off = 1; off < 512; off <<= 1) {
        float u_ = (t >= off) ? sc[t - off] : 0.f;
        __syncthreads();
        inc += u_;
        sc[t] = inc;
        __syncthreads();
      }
      poff[t] = inc - v;
      if (t == 511) poff[CHUNKS] = inc;
      if (t == 0) pl[N] = 0.f;
    }
    __syncthreads();
    {  // scalar exclusive suffix over totb_sc
      int rc = 511 - t;
      float v = totb_sc[rc];
      sc[t] = v;
      __syncthreads();
      float inc = v;
#pragma unroll
      for (int off = 1; off < 512; off <<= 1) {
        float u_ = (t >= off) ? sc[t - off] : 0.f;
        __syncthreads();
        inc += u_;
        sc[t] = inc;
        __syncthreads();
      }
      soff[rc] = inc - v;
      if (t == 0) {
        soff[CHUNKS] = 0.f;
        sl[N] = 0.f;
      }
    }
  }
}

// K4: per (row, dim): combine global offset + local scan at split k; ELU.
// (verified baseline code, unchanged)
__global__ __launch_bounds__(256) void k4_out(
    const float* __restrict__ f1, const int* __restrict__ ksplit,
    const float* __restrict__ off_s, const float* __restrict__ off_b,
    const float* __restrict__ poff, const float* __restrict__ soff,
    const float* __restrict__ Pl, const float* __restrict__ Sl,
    const float* __restrict__ pl, const float* __restrict__ sl,
    float* __restrict__ out) {
  int g = blockIdx.x * 256 + threadIdx.x;
  int row = g >> 6, dd = g & 63;
  float f1v = f1[row];
  int k = ksplit[row];
  int c = k >> 4;  // CROWS == 16; k == N -> sentinel chunk
  float e1 = expf(f1v), e2 = expf(0.2f * f1v);
  float Sv = off_b[c * D + dd] + Sl[(size_t)k * D + dd];
  float Pv = off_s[c * D + dd] + Pl[(size_t)k * D + dd];
  float num = e1 * Sv + e2 * Pv;
  float den = e1 * (soff[c] + sl[k]) + e2 * (poff[c] + pl[k]);
  float v = num / den;
  out[g] = v > 0.f ? v : expm1f(v);
}

extern "C" void kernel_launch(void* const* d_in, const int* in_sizes, int n_in,
                              void* d_out, int out_size, void* d_ws,
                              size_t ws_size, hipStream_t stream) {
  const float* x = (const float*)d_in[0];
  const float* Wt = (const float*)d_in[1];
  const float* a1 = (const float*)d_in[2];
  const float* b1 = (const float*)d_in[3];
  const float* a2 = (const float*)d_in[4];
  const float* b2 = (const float*)d_in[5];
  float* out = (float*)d_out;

  u64* key64 = (u64*)d_ws;
  u64* thrkey = key64 + N;
  float* ws = (float*)(thrkey + N);
  float* h = ws;          ws += N * D;
  float* f1 = ws;         ws += N;
  float* f2v = ws;        ws += N;
  float* wsm = ws;        ws += N;
  float* wbg = ws;        ws += N;
  int* perm = (int*)ws;   ws += N;
  int* ksplit = (int*)ws; ws += N;
  float* Pl = ws;         ws += (size_t)(N + 1) * D;
  float* Sl = ws;         ws += (size_t)(N + 1) * D;
  float* tot_s = ws;      ws += CHUNKS * D;
  float* tot_b = ws;      ws += CHUNKS * D;
  float* off_s = ws;      ws += (CHUNKS + 1) * D;
  float* off_b = ws;      ws += (CHUNKS + 1) * D;
  float* pl = ws;         ws += (N + 1);
  float* sl = ws;         ws += (N + 1);
  float* tots_sc = ws;    ws += CHUNKS;
  float* totb_sc = ws;    ws += CHUNKS;
  float* poff = ws;       ws += (CHUNKS + 1);
  float* soff = ws;       ws += (CHUNKS + 1);

  k1_gemm<<<N / 16, 256, 0, stream>>>(x, Wt, a1, b1, a2, b2, h, f1, f2v,
                                      key64, thrkey);
  k2_rank<<<NQ / 32, 256, 0, stream>>>(key64, thrkey, f2v, perm, wsm, wbg,
                                       ksplit);
  k3_scan<<<CHUNKS / 4, 256, 0, stream>>>(h, perm, wsm, wbg, Pl, Sl, pl, sl,
                                          tot_s, tot_b, tots_sc, totb_sc);
  k3b_offsets<<<129, 512, 0, stream>>>(tot_s, tot_b, tots_sc, totb_sc, off_s,
                                       off_b, poff, soff, Pl, Sl, pl, sl);
  k4_out<<<(N * D) / 256, 256, 0, stream>>>(f1, ksplit, off_s, off_b, poff,
                                            soff, Pl, Sl, pl, sl, out);
}